// Round 8
// baseline (111.684 us; speedup 1.0000x reference)
//
#include <hip/hip_runtime.h>
#include <hip/hip_bf16.h>

#define SDIM 192
#define S2 (SDIM*SDIM)        // 36864
#define S3 ((size_t)SDIM*S2)  // 7077888
#define NCH 5
#define RAD 4                 // window 9

// ---- KA: one d-slice, 8 output rows, full 192-w strip per block ----
#define STRH 8
#define RROW 16               // staged rows (8 + 2*4 halo)
#define RST 200               // uint stride per raw row: packed {i,j} bf16, 4+192+4 cols
#define WSTR 97               // uint (bf16x2) stride per wf row
#define NSTRIP (SDIM/STRH)    // 24

// ---- KB: D-axis add/sub sliding window, uint4 per thread, 1-wave blocks ----
#define KB_THR 64
#define KB_KBC 8                            // w-positions per thread (one uint4 = 8 bf16)
#define KB_POSB (S2/(KB_THR*KB_KBC))        // 72
#define KB_DCH 8
#define KB_NDC (SDIM/KB_DCH)                // 24
#define KB_GRID (KB_POSB*KB_NDC)            // 1728
#define NPART KB_GRID

__device__ __forceinline__ unsigned short f2bfu(float x) {
    __hip_bfloat16 h = __float2bfloat16(x);
    unsigned short u; __builtin_memcpy(&u, &h, 2); return u;
}
__device__ __forceinline__ unsigned packbf(float lo, float hi) {
    return (unsigned)f2bfu(lo) | ((unsigned)f2bfu(hi) << 16);
}
__device__ __forceinline__ float ulo(unsigned u) { return __uint_as_float(u << 16); }
__device__ __forceinline__ float uhi(unsigned u) { return __uint_as_float(u & 0xffff0000u); }

// 9-tap sliding sum over pv[0..10] -> 3 bf16 outputs into LDS
__device__ __forceinline__ void store3(unsigned short* wf16, int cidx, int row, int c0,
                                       const float* pv) {
    float s = 0.f;
#pragma unroll
    for (int k = 0; k < 9; ++k) s += pv[k];
    const float o1 = s - pv[0] + pv[9];
    const float o2 = o1 - pv[1] + pv[10];
    const int base = (cidx * RROW + row) * (2 * WSTR) + c0;
    wf16[base + 0] = f2bfu(s);
    wf16[base + 1] = f2bfu(o1);
    wf16[base + 2] = f2bfu(o2);
}

// ---------------- KA: W + H 9-tap (zero-padded) of the 5 product channels ----------------
__global__ __launch_bounds__(256) void ka_wh(const float* __restrict__ pred,
                                             const float* __restrict__ tgt,
                                             unsigned* __restrict__ BU) {
    const int b = blockIdx.x;              // d*24 + strip
    const int strip = b % NSTRIP;
    const int d = b / NSTRIP;
    const int h0 = strip * STRH;
    const size_t dbase = (size_t)d * S2;
    const int t = threadIdx.x;

    __shared__ unsigned IJ[RROW][RST];          // packed {i(lo), j(hi)} bf16 — 12.8 KB
    __shared__ unsigned wfU[NCH][RROW][WSTR];   // bf16x2 over w — 31.0 KB

    // zero the 4-col pads on both w-edges: cols 0..3 and 196..199 (one uint per col!)
    if (t < RROW * 8) {
        const int r = t >> 3, p = t & 7;
        const int col = (p < 4) ? p : (192 + p);   // 0..3 / 196..199
        IJ[r][col] = 0u;
    }
    // stage interior rows: float4 global loads -> packed bf16{i,j} uint4 LDS writes
    const float4* tg4 = (const float4*)tgt;
    const float4* pr4 = (const float4*)pred;
#pragma unroll
    for (int it = 0; it < 3; ++it) {
        const int u = t + 256 * it;            // 0..767
        const int r = u / 48, q = u % 48;
        const int hh = h0 - RAD + r;
        float4 vi = make_float4(0.f, 0.f, 0.f, 0.f), vj = vi;
        if (hh >= 0 && hh < SDIM) {
            const size_t gi = (dbase + (size_t)hh * SDIM) / 4 + q;
            vi = tg4[gi]; vj = pr4[gi];
        }
        uint4 w;
        w.x = packbf(vi.x, vj.x); w.y = packbf(vi.y, vj.y);
        w.z = packbf(vi.z, vj.z); w.w = packbf(vi.w, vj.w);
        *(uint4*)&IJ[r][4 + 4 * q] = w;
    }
    __syncthreads();

    // W phase: wave owns rows wv, wv+4, wv+8, wv+12; lane owns 3 consecutive output cols.
    unsigned short* wf16 = (unsigned short*)wfU;
    const int wv = t >> 6, lane = t & 63;
    const int c0 = lane * 3;
#pragma unroll
    for (int rr = 0; rr < 4; ++rr) {
        const int row = wv + rr * 4;
        float fi[11], fj[11];
#pragma unroll
        for (int k = 0; k < 11; ++k) {
            const unsigned u = IJ[row][c0 + k];
            fi[k] = ulo(u); fj[k] = uhi(u);
        }
        float pv[11];
#pragma unroll
        for (int k = 0; k < 11; ++k) pv[k] = fi[k];
        store3(wf16, 0, row, c0, pv);
#pragma unroll
        for (int k = 0; k < 11; ++k) pv[k] = fj[k];
        store3(wf16, 1, row, c0, pv);
#pragma unroll
        for (int k = 0; k < 11; ++k) pv[k] = fi[k] * fi[k];
        store3(wf16, 2, row, c0, pv);
#pragma unroll
        for (int k = 0; k < 11; ++k) pv[k] = fj[k] * fj[k];
        store3(wf16, 3, row, c0, pv);
#pragma unroll
        for (int k = 0; k < 11; ++k) pv[k] = fi[k] * fj[k];
        store3(wf16, 4, row, c0, pv);
    }
    __syncthreads();

    // H phase: thread owns a (channel, w-pair) column; sliding 9-sum over h, 8 outputs.
#pragma unroll
    for (int it = 0; it < 2; ++it) {
        const int col = t + 256 * it;          // 0..479 = c*96 + wp
        if (col < NCH * 96) {
            const int c = col / 96, wp = col % 96;
            float lo[RROW], hi[RROW];
#pragma unroll
            for (int r = 0; r < RROW; ++r) {
                const unsigned v = wfU[c][r][wp];
                lo[r] = ulo(v); hi[r] = uhi(v);
            }
            float slo = 0.f, shi = 0.f;
#pragma unroll
            for (int r = 0; r < 9; ++r) { slo += lo[r]; shi += hi[r]; }
            unsigned* dst = BU + (size_t)c * (S3 / 2) + (dbase + (size_t)h0 * SDIM) / 2 + wp;
            dst[0] = packbf(slo, shi);
#pragma unroll
            for (int hr = 1; hr < STRH; ++hr) {
                slo += lo[hr + 8] - lo[hr - 1];
                shi += hi[hr + 8] - hi[hr - 1];
                dst[hr * (SDIM / 2)] = packbf(slo, shi);
            }
        }
    }
}

// ---------------- KB: D-axis add/sub sliding window, uint4 loads, 1-wave blocks ----------------
#define SLICE4(s, OP) { const size_t sb = ((size_t)(s) * S2 + pos0) >> 3; \
    _Pragma("unroll") for (int c = 0; c < NCH; ++c) { \
        const uint4 v = B4[(size_t)c * (S3 >> 3) + sb]; \
        z[c][0] OP ulo(v.x); z[c][1] OP uhi(v.x); \
        z[c][2] OP ulo(v.y); z[c][3] OP uhi(v.y); \
        z[c][4] OP ulo(v.z); z[c][5] OP uhi(v.z); \
        z[c][6] OP ulo(v.w); z[c][7] OP uhi(v.w); } }

__global__ __launch_bounds__(KB_THR, 4) void kb_d_cc(const unsigned* __restrict__ BU,
                                                     float* __restrict__ partials) {
    const int bid = blockIdx.x;
    const int dc = bid / KB_POSB;
    const int pb = bid % KB_POSB;
    const int d0 = dc * KB_DCH;
    const int pos0 = pb * (KB_THR * KB_KBC) + threadIdx.x * KB_KBC;
    const uint4* B4 = (const uint4*)BU;

    float z[NCH][KB_KBC];
#pragma unroll
    for (int c = 0; c < NCH; ++c)
#pragma unroll
        for (int i = 0; i < KB_KBC; ++i) z[c][i] = 0.f;

    // warm up: window for output d0 (slices d0-4..d0+4, zero-padded)
#pragma unroll
    for (int dd = -RAD; dd <= RAD; ++dd) {
        const int s = d0 + dd;
        if (s >= 0 && s < SDIM) SLICE4(s, +=)
    }

    const float inv = 1.0f / 729.0f;
    const float eps = 1.1920929e-07f;      // np.finfo(float32).eps
    float acc = 0.f;

#pragma unroll
    for (int k = 0; k < KB_DCH; ++k) {
        const int d = d0 + k;
#pragma unroll
        for (int i = 0; i < KB_KBC; ++i) {
            const float mu1 = z[0][i] * inv;
            const float mu2 = z[1][i] * inv;
            const float sg1 = z[2][i] * inv - mu1 * mu1;
            const float sg2 = z[3][i] * inv - mu2 * mu2;
            const float s12 = z[4][i] * inv - mu1 * mu2;
            acc += (s12 * s12) * __builtin_amdgcn_rcpf(sg1 * sg2 + eps);
        }
        const int da = d + RAD + 1;
        const int ds = d - RAD;
        if (da < SDIM) SLICE4(da, +=)
        if (ds >= 0)   SLICE4(ds, -=)
    }

    // wave-level deterministic reduction (single-wave block)
#pragma unroll
    for (int off = 32; off > 0; off >>= 1)
        acc += __shfl_down(acc, off, 64);
    if (threadIdx.x == 0) partials[bid] = acc;
}

// ---------------- K4: final deterministic reduction ----------------
__global__ __launch_bounds__(256) void k4_finalize(const float* __restrict__ partials,
                                                   float* __restrict__ out) {
    __shared__ float sm[256];
    float s = 0.f;
    for (int i = threadIdx.x; i < NPART; i += 256) s += partials[i];
    sm[threadIdx.x] = s;
    __syncthreads();
#pragma unroll
    for (int o = 128; o > 0; o >>= 1) {
        if (threadIdx.x < o) sm[threadIdx.x] += sm[threadIdx.x + o];
        __syncthreads();
    }
    if (threadIdx.x == 0) out[0] = 1.0f - sm[0] / (float)((size_t)SDIM * S2);
}

extern "C" void kernel_launch(void* const* d_in, const int* in_sizes, int n_in,
                              void* d_out, int out_size, void* d_ws, size_t ws_size,
                              hipStream_t stream) {
    const float* pred = (const float*)d_in[0];
    const float* tgt  = (const float*)d_in[1];
    float* out = (float*)d_out;

    const size_t b_bytes = (size_t)NCH * S3 * sizeof(__hip_bfloat16);   // ~70.8 MB
    const size_t b_pad = (b_bytes + 255) & ~(size_t)255;

    unsigned* BU = (unsigned*)d_ws;
    float* partials = (float*)((char*)d_ws + b_pad);

    ka_wh<<<SDIM * NSTRIP, 256, 0, stream>>>(pred, tgt, BU);
    kb_d_cc<<<KB_GRID, KB_THR, 0, stream>>>(BU, partials);
    k4_finalize<<<1, 256, 0, stream>>>(partials, out);
}

// Round 9
// 82.154 us; speedup vs baseline: 1.3595x; 1.3595x over previous
//
#include <hip/hip_runtime.h>
#include <hip/hip_bf16.h>

#define SDIM 192
#define S2 (SDIM*SDIM)        // 36864
#define S3 ((size_t)SDIM*S2)  // 7077888
#define NCH 5
#define RAD 4                 // window 9

// ---- KA: one d-slice, 6 output rows, full 192-w strip per block ----
#define STRH 6
#define RROW 14               // staged rows (6 + 2*4 halo)
#define RST 200               // uint stride per raw row: packed {i,j} bf16, 4+192+4 cols
#define WSTR 96               // uint (bf16x2) stride per wf row
#define NSTRIP (SDIM/STRH)    // 32

// ---- KB: D-axis add/sub sliding window, uint2 (4 bf16) per thread, 256-thr blocks ----
#define KB_KBC 4                            // w-positions per thread (one uint2 = 4 bf16)
#define KB_POSB (S2/(256*KB_KBC))           // 36
#define KB_DCH 8
#define KB_NDC (SDIM/KB_DCH)                // 24
#define KB_GRID (KB_POSB*KB_NDC)            // 864
#define NPART KB_GRID

__device__ __forceinline__ unsigned short f2bfu(float x) {
    __hip_bfloat16 h = __float2bfloat16(x);
    unsigned short u; __builtin_memcpy(&u, &h, 2); return u;
}
__device__ __forceinline__ unsigned packbf(float lo, float hi) {
    return (unsigned)f2bfu(lo) | ((unsigned)f2bfu(hi) << 16);
}
__device__ __forceinline__ float ulo(unsigned u) { return __uint_as_float(u << 16); }
__device__ __forceinline__ float uhi(unsigned u) { return __uint_as_float(u & 0xffff0000u); }

// 9-tap sliding sum over pv[0..10] -> 3 bf16 outputs into LDS
__device__ __forceinline__ void store3(unsigned short* wf16, int cidx, int row, int c0,
                                       const float* pv) {
    float s = 0.f;
#pragma unroll
    for (int k = 0; k < 9; ++k) s += pv[k];
    const float o1 = s - pv[0] + pv[9];
    const float o2 = o1 - pv[1] + pv[10];
    const int base = (cidx * RROW + row) * (2 * WSTR) + c0;
    wf16[base + 0] = f2bfu(s);
    wf16[base + 1] = f2bfu(o1);
    wf16[base + 2] = f2bfu(o2);
}

// ---------------- KA: W + H 9-tap (zero-padded) of the 5 product channels ----------------
__global__ __launch_bounds__(256) void ka_wh(const float* __restrict__ pred,
                                             const float* __restrict__ tgt,
                                             unsigned* __restrict__ BU) {
    const int b = blockIdx.x;              // d*NSTRIP + strip
    const int strip = b % NSTRIP;
    const int d = b / NSTRIP;
    const int h0 = strip * STRH;
    const size_t dbase = (size_t)d * S2;
    const int t = threadIdx.x;

    __shared__ unsigned IJ[RROW][RST];          // packed {i(lo), j(hi)} bf16 — 11.2 KB
    __shared__ unsigned wfU[NCH][RROW][WSTR];   // bf16x2 over w — 26.9 KB

    // zero the 4-col pads on both w-edges: cols 0..3 and 196..199
    if (t < RROW * 8) {
        const int r = t >> 3, p = t & 7;
        const int col = (p < 4) ? p : (192 + p);   // 0..3 / 196..199
        IJ[r][col] = 0u;
    }
    // stage interior rows: float4 global loads -> packed bf16{i,j} uint4 LDS writes
    const float4* tg4 = (const float4*)tgt;
    const float4* pr4 = (const float4*)pred;
#pragma unroll
    for (int it = 0; it < 3; ++it) {
        const int u = t + 256 * it;            // 0..671
        if (u < RROW * 48) {
            const int r = u / 48, q = u % 48;
            const int hh = h0 - RAD + r;
            float4 vi = make_float4(0.f, 0.f, 0.f, 0.f), vj = vi;
            if (hh >= 0 && hh < SDIM) {
                const size_t gi = (dbase + (size_t)hh * SDIM) / 4 + q;
                vi = tg4[gi]; vj = pr4[gi];
            }
            uint4 w;
            w.x = packbf(vi.x, vj.x); w.y = packbf(vi.y, vj.y);
            w.z = packbf(vi.z, vj.z); w.w = packbf(vi.w, vj.w);
            *(uint4*)&IJ[r][4 + 4 * q] = w;
        }
    }
    __syncthreads();

    // W phase: wave owns rows wv, wv+4, wv+8, wv+12 (guard <RROW); lane owns 3 output cols.
    unsigned short* wf16 = (unsigned short*)wfU;
    const int wv = t >> 6, lane = t & 63;
    const int c0 = lane * 3;
#pragma unroll
    for (int rr = 0; rr < 4; ++rr) {
        const int row = wv + rr * 4;
        if (row < RROW) {
            float fi[11], fj[11];
#pragma unroll
            for (int k = 0; k < 11; ++k) {
                const unsigned u = IJ[row][c0 + k];
                fi[k] = ulo(u); fj[k] = uhi(u);
            }
            float pv[11];
#pragma unroll
            for (int k = 0; k < 11; ++k) pv[k] = fi[k];
            store3(wf16, 0, row, c0, pv);
#pragma unroll
            for (int k = 0; k < 11; ++k) pv[k] = fj[k];
            store3(wf16, 1, row, c0, pv);
#pragma unroll
            for (int k = 0; k < 11; ++k) pv[k] = fi[k] * fi[k];
            store3(wf16, 2, row, c0, pv);
#pragma unroll
            for (int k = 0; k < 11; ++k) pv[k] = fj[k] * fj[k];
            store3(wf16, 3, row, c0, pv);
#pragma unroll
            for (int k = 0; k < 11; ++k) pv[k] = fi[k] * fj[k];
            store3(wf16, 4, row, c0, pv);
        }
    }
    __syncthreads();

    // H phase: thread owns a (channel, w-pair) column; sliding 9-sum over h, STRH outputs.
#pragma unroll
    for (int it = 0; it < 2; ++it) {
        const int col = t + 256 * it;          // 0..479 = c*96 + wp
        if (col < NCH * 96) {
            const int c = col / 96, wp = col % 96;
            float lo[RROW], hi[RROW];
#pragma unroll
            for (int r = 0; r < RROW; ++r) {
                const unsigned v = wfU[c][r][wp];
                lo[r] = ulo(v); hi[r] = uhi(v);
            }
            float slo = 0.f, shi = 0.f;
#pragma unroll
            for (int r = 0; r < 9; ++r) { slo += lo[r]; shi += hi[r]; }
            unsigned* dst = BU + (size_t)c * (S3 / 2) + (dbase + (size_t)h0 * SDIM) / 2 + wp;
            dst[0] = packbf(slo, shi);
#pragma unroll
            for (int hr = 1; hr < STRH; ++hr) {
                slo += lo[hr + 8] - lo[hr - 1];
                shi += hi[hr + 8] - hi[hr - 1];
                dst[hr * (SDIM / 2)] = packbf(slo, shi);
            }
        }
    }
}

// ---------------- KB: D-axis add/sub sliding window with uint2 loads + cc + reduce ----------------
#define SLICE2(s, OP) { const size_t sb = ((size_t)(s) * S2 + pos0) >> 2; \
    _Pragma("unroll") for (int c = 0; c < NCH; ++c) { \
        const uint2 v = B2[(size_t)c * (S3 >> 2) + sb]; \
        z[c][0] OP ulo(v.x); z[c][1] OP uhi(v.x); \
        z[c][2] OP ulo(v.y); z[c][3] OP uhi(v.y); } }

__global__ __launch_bounds__(256) void kb_d_cc(const unsigned* __restrict__ BU,
                                               float* __restrict__ partials) {
    const int bid = blockIdx.x;
    const int dc = bid / KB_POSB;
    const int pb = bid % KB_POSB;
    const int d0 = dc * KB_DCH;
    const int pos0 = pb * (256 * KB_KBC) + threadIdx.x * KB_KBC;
    const uint2* B2 = (const uint2*)BU;

    float z[NCH][KB_KBC];
#pragma unroll
    for (int c = 0; c < NCH; ++c)
#pragma unroll
        for (int i = 0; i < KB_KBC; ++i) z[c][i] = 0.f;

    // warm up: window for output d0 (slices d0-4..d0+4, zero-padded)
#pragma unroll
    for (int dd = -RAD; dd <= RAD; ++dd) {
        const int s = d0 + dd;
        if (s >= 0 && s < SDIM) SLICE2(s, +=)
    }

    const float inv = 1.0f / 729.0f;
    const float eps = 1.1920929e-07f;      // np.finfo(float32).eps
    float acc = 0.f;

#pragma unroll
    for (int k = 0; k < KB_DCH; ++k) {
        const int d = d0 + k;
#pragma unroll
        for (int i = 0; i < KB_KBC; ++i) {
            const float mu1 = z[0][i] * inv;
            const float mu2 = z[1][i] * inv;
            const float sg1 = z[2][i] * inv - mu1 * mu1;
            const float sg2 = z[3][i] * inv - mu2 * mu2;
            const float s12 = z[4][i] * inv - mu1 * mu2;
            acc += (s12 * s12) * __builtin_amdgcn_rcpf(sg1 * sg2 + eps);
        }
        const int da = d + RAD + 1;
        const int ds = d - RAD;
        if (da < SDIM) SLICE2(da, +=)
        if (ds >= 0)   SLICE2(ds, -=)
    }

    __shared__ float red[256];
    red[threadIdx.x] = acc;
    __syncthreads();
#pragma unroll
    for (int o = 128; o > 0; o >>= 1) {
        if (threadIdx.x < o) red[threadIdx.x] += red[threadIdx.x + o];
        __syncthreads();
    }
    if (threadIdx.x == 0) partials[bid] = red[0];
}

// ---------------- K4: final deterministic reduction ----------------
__global__ __launch_bounds__(256) void k4_finalize(const float* __restrict__ partials,
                                                   float* __restrict__ out) {
    __shared__ float sm[256];
    float s = 0.f;
    for (int i = threadIdx.x; i < NPART; i += 256) s += partials[i];
    sm[threadIdx.x] = s;
    __syncthreads();
#pragma unroll
    for (int o = 128; o > 0; o >>= 1) {
        if (threadIdx.x < o) sm[threadIdx.x] += sm[threadIdx.x + o];
        __syncthreads();
    }
    if (threadIdx.x == 0) out[0] = 1.0f - sm[0] / (float)((size_t)SDIM * S2);
}

extern "C" void kernel_launch(void* const* d_in, const int* in_sizes, int n_in,
                              void* d_out, int out_size, void* d_ws, size_t ws_size,
                              hipStream_t stream) {
    const float* pred = (const float*)d_in[0];
    const float* tgt  = (const float*)d_in[1];
    float* out = (float*)d_out;

    const size_t b_bytes = (size_t)NCH * S3 * sizeof(__hip_bfloat16);   // ~70.8 MB
    const size_t b_pad = (b_bytes + 255) & ~(size_t)255;

    unsigned* BU = (unsigned*)d_ws;
    float* partials = (float*)((char*)d_ws + b_pad);

    ka_wh<<<SDIM * NSTRIP, 256, 0, stream>>>(pred, tgt, BU);
    kb_d_cc<<<KB_GRID, 256, 0, stream>>>(BU, partials);
    k4_finalize<<<1, 256, 0, stream>>>(partials, out);
}